// Round 10
// baseline (222.046 us; speedup 1.0000x reference)
//
#include <hip/hip_runtime.h>

// LNCC DEBUG1: num = (tp_sum - (p_sum/729)*t_sum)^2 + 1e-5, 9^3 box sums, SAME zero pad.
//
// R14: champion structure VERBATIM (R8's 5-step iteration, 2 LDS-only barriers,
// register prefetch, post-bar2 finalize) re-parameterized to 768-thread blocks /
// 32x24 tiles. Rationale: OccupancyPercent ~42% for all VGPR 48-64 variants vs 82%
// at VGPR 32 suggests only ONE 1024-thread block resides per CU -- champion sits
// exactly on BOTH hard edges (2x16 waves = 32-wave cap; 8 waves/SIMD x 64-granular
// VGPR = 512-reg boundary). 768t blocks: 2 blocks = 24 waves (slack 8), 6 waves/SIMD
// x 64 = 384 regs (slack 128). Tile 32x24 makes L-decode = 3 fields x 32 rows x 8
// quads = 768 = exactly every thread (no lactive guard). z-chunks ~38/39 (halo
// 1.21x vs 1.30x) -> total busy work -8% vs champion despite xy-halo 1.67x.
// Grid 96 xy-tiles x 5 z-chunks = 480 blocks = one 94%-full residency round.
// R13 lesson: no setprio (regressed +7%).

#define N 192
#define RSTRIDE 34   // rowT stride: even (8B float2 aligned); 4*34 mod 32 = 8 -> 2-way free

// LDS-only barrier: drain LDS ops, then barrier. No vmcnt drain (prefetch stays in flight).
#define LDS_BARRIER() asm volatile("s_waitcnt lgkmcnt(0)\n\ts_barrier" ::: "memory")

__global__ __launch_bounds__(768, 2)
void lncc_kernel(const float* __restrict__ t_in,
                 const float* __restrict__ p_in,
                 float* __restrict__ out)
{
    // rowT[f][outx 32][ry 32]: transposed x-blurred row sums
    __shared__ __align__(16) float rowT[3 * 32 * RSTRIDE];   // 13.1 KB
    // pcol[f][y 24][x 32]: per-plane 2D (9x9) box sums
    __shared__ float pcol[3 * 24 * 32];                      // 9.2 KB

    // ---- work assignment: 480 blocks = 96 xy tiles x 5 z-chunks {39,39,38,38,38}
    const int bid = blockIdx.x;
    const int xy  = bid / 5;
    const int zi  = bid % 5;
    const int Z   = (zi < 2) ? 39 : 38;
    const int z0  = (zi < 2) ? zi * 39 : 78 + (zi - 2) * 38;

    const int b  = xy / 48;               // batch 0..1
    const int t6 = xy % 48;
    const int y0 = (t6 / 6) * 24;         // 8 y-tiles of 24
    const int x0 = (t6 % 6) * 32;         // 6 x-tiles of 32
    const int tid = threadIdx.x;

    // ---- L (row-sum) decode: 3 fields x 32 rows x 8 x-quads = 768 = ALL threads
    const int  lf   = tid >> 8;           // 0=t 1=p 2=tp (wave-uniform: 256 = 4 waves)
    const int  ls   = tid & 255;
    const int  lry  = ls >> 3;            // raw row 0..31
    const int  lxq  = ls & 7;             // x quad 0..7
    const int  lgy  = y0 - 4 + lry;
    const int  lgx0 = x0 - 4 + 4 * lxq;   // 16B-aligned quad base
    const bool lyok = ((unsigned)lgy < (unsigned)N);

    // ---- C (col-sum) decode: 3 fields x 6 y-quads x 32 x = 576 slots (9 waves)
    const int  cf  = tid / 192;           // wave-uniform (192 = 3 waves)
    const int  cs  = tid - cf * 192;
    const int  cyq = cs >> 5;             // y-quad 0..5
    const int  cx  = cs & 31;
    const bool cactive = (tid < 576);

    // ---- G decode: every thread owns output column (gx,gy), gy 0..23
    const int gx = tid & 31;
    const int gy = tid >> 5;

    const size_t plane = (size_t)N * N;
    const float* tb = t_in + (size_t)b * N * plane;
    const float* pb = p_in + (size_t)b * N * plane;
    float*       ob = out  + (size_t)b * N * plane
                           + (size_t)(y0 + gy) * N + (x0 + gx);

    // loop-invariant row base pointers (y clamped; loads stay guarded by lyok)
    const int lgyc = lyok ? lgy : 0;
    const float* const trow = tb + (size_t)lgyc * N;
    const float* const prow = pb + (size_t)lgyc * N;
    const float* const arow = (lf == 1) ? prow : trow;   // wave-uniform a-source select

    float ring_t[9], ring_p[9], ring_tp[9];
    float sum_t = 0.f, sum_p = 0.f, sum_tp = 0.f;
    #pragma unroll
    for (int i = 0; i < 9; ++i) { ring_t[i] = 0.f; ring_p[i] = 0.f; ring_tp[i] = 0.f; }

    const float4 z4 = make_float4(0.f, 0.f, 0.f, 0.f);
    float4 cur0 = z4, cur1 = z4, cur2 = z4;     // row-sum-ready 12 floats for plane i

    // ---- prologue: load + finalize plane 0 (one exposed latency per block)
    {
        const int zp0 = z0 - 4;
        if (((unsigned)zp0 < (unsigned)N) && lyok) {
            const float* ar = arow + (size_t)zp0 * plane;
            const float* cr = prow + (size_t)zp0 * plane;
            float4 a[3], c[3];
            #pragma unroll
            for (int q = 0; q < 3; ++q) {
                a[q] = z4; c[q] = z4;
                const int gxq = lgx0 + 4 * q;
                if ((unsigned)gxq < (unsigned)N) {
                    a[q] = *(const float4*)(ar + gxq);
                    if (lf == 2) c[q] = *(const float4*)(cr + gxq);
                }
            }
            if (lf == 2) {
                #pragma unroll
                for (int q = 0; q < 3; ++q) {
                    a[q].x *= c[q].x; a[q].y *= c[q].y;
                    a[q].z *= c[q].z; a[q].w *= c[q].w;
                }
            }
            cur0 = a[0]; cur1 = a[1]; cur2 = a[2];
        }
    }

    #pragma unroll 1
    for (int k = 0; k < 6; ++k) {
      #pragma unroll
      for (int r = 0; r < 9; ++r) {
        const int i  = k * 9 + r;
        if (i >= Z + 8) break;               // block-uniform: Z, i uniform
        const int zp = z0 - 4 + i;           // plane i
        const int zn = zp + 1;               // plane i+1
        const bool vi = ((unsigned)zp < (unsigned)N);
        const bool vn = (i + 1 < Z + 8) && ((unsigned)zn < (unsigned)N);

        // ---- 1. issue loads for plane i+1 (consumed at step 5) ----
        float4 fa0 = z4, fa1 = z4, fa2 = z4, fc0 = z4, fc1 = z4, fc2 = z4;
        if (vn && lyok) {
            const float* ar = arow + (size_t)zn * plane;
            const float* cr = prow + (size_t)zn * plane;
            const int g0 = lgx0, g1 = lgx0 + 4, g2 = lgx0 + 8;
            if ((unsigned)g0 < (unsigned)N) {
                fa0 = *(const float4*)(ar + g0);
                if (lf == 2) fc0 = *(const float4*)(cr + g0);
            }
            if ((unsigned)g1 < (unsigned)N) {
                fa1 = *(const float4*)(ar + g1);
                if (lf == 2) fc1 = *(const float4*)(cr + g1);
            }
            if ((unsigned)g2 < (unsigned)N) {
                fa2 = *(const float4*)(ar + g2);
                if (lf == 2) fc2 = *(const float4*)(cr + g2);
            }
        }

        // ---- 2. RowSum(plane i) from cur -> rowT (all 768 threads) ----
        if (vi) {
            const float v0 = cur0.x, v1 = cur0.y, v2  = cur0.z, v3  = cur0.w;
            const float v4 = cur1.x, v5 = cur1.y, v6  = cur1.z, v7  = cur1.w;
            const float v8 = cur2.x, v9 = cur2.y, v10 = cur2.z, v11 = cur2.w;
            float s0 = ((v0+v1) + (v2+v3)) + ((v4+v5) + (v6+v7)) + v8;
            float s1 = s0 - v0 + v9;
            float s2 = s1 - v1 + v10;
            float s3 = s2 - v2 + v11;
            float* wp = &rowT[(lf * 32 + 4 * lxq) * RSTRIDE + lry];
            wp[0]           = s0;
            wp[RSTRIDE]     = s1;
            wp[2 * RSTRIDE] = s2;
            wp[3 * RSTRIDE] = s3;
        }
        LDS_BARRIER();

        // ---- 3. ColSum(plane i): rowT -> pcol ----
        if (vi && cactive) {
            const float* rb = &rowT[(cf * 32 + cx) * RSTRIDE + 4 * cyq];
            const float2 u0 = *(const float2*)(rb + 0);
            const float2 u1 = *(const float2*)(rb + 2);
            const float2 u2 = *(const float2*)(rb + 4);
            const float2 u3 = *(const float2*)(rb + 6);
            const float2 u4 = *(const float2*)(rb + 8);
            const float2 u5 = *(const float2*)(rb + 10);
            const float w0=u0.x, w1=u0.y, w2=u1.x,  w3=u1.y;
            const float w4=u2.x, w5=u2.y, w6=u3.x,  w7=u3.y;
            const float w8=u4.x, w9=u4.y, w10=u5.x, w11=u5.y;
            float c0 = ((w0+w1)+(w2+w3)) + ((w4+w5)+(w6+w7)) + w8;
            float c1 = c0 - w0 + w9;
            float c2 = c1 - w1 + w10;
            float c3 = c2 - w2 + w11;
            float* pc = &pcol[cf * 768 + (4 * cyq) * 32 + cx];
            pc[0]  = c0;
            pc[32] = c1;
            pc[64] = c2;
            pc[96] = c3;
        }
        LDS_BARRIER();

        // ---- 4. Gather(plane i), z-ring (slot r == i%9), output ----
        float Pt = 0.f, Pp = 0.f, Ptp = 0.f;
        if (vi) {
            Pt  = pcol[       gy * 32 + gx];
            Pp  = pcol[ 768 + gy * 32 + gx];
            Ptp = pcol[1536 + gy * 32 + gx];
        }
        sum_t  += Pt  - ring_t[r];  ring_t[r]  = Pt;
        sum_p  += Pp  - ring_p[r];  ring_p[r]  = Pp;
        sum_tp += Ptp - ring_tp[r]; ring_tp[r] = Ptp;
        if (i >= 8) {
            const float cross = sum_tp - (sum_p * (1.0f / 729.0f)) * sum_t;
            ob[(size_t)(z0 + i - 8) * plane] = cross * cross + 1e-5f;
        }

        // ---- 5. finalize: cur = (lf==2 ? a*c : a)  (loads have landed by now) ----
        if (vn) {
            float4 A0 = fa0, A1 = fa1, A2 = fa2;
            if (lf == 2) {
                A0.x *= fc0.x; A0.y *= fc0.y; A0.z *= fc0.z; A0.w *= fc0.w;
                A1.x *= fc1.x; A1.y *= fc1.y; A1.z *= fc1.z; A1.w *= fc1.w;
                A2.x *= fc2.x; A2.y *= fc2.y; A2.z *= fc2.z; A2.w *= fc2.w;
            }
            cur0 = A0; cur1 = A1; cur2 = A2;
        }
      }
    }
}

extern "C" void kernel_launch(void* const* d_in, const int* in_sizes, int n_in,
                              void* d_out, int out_size, void* d_ws, size_t ws_size,
                              hipStream_t stream) {
    const float* y_true = (const float*)d_in[0];
    const float* y_pred = (const float*)d_in[1];
    float* out = (float*)d_out;
    dim3 grid(480);
    dim3 block(768);
    hipLaunchKernelGGL(lncc_kernel, grid, block, 0, stream, y_true, y_pred, out);
}